// Round 10
// baseline (92.517 us; speedup 1.0000x reference)
//
#include <hip/hip_runtime.h>

#define P_SZ 1152
#define DP 8
#define DS 16
#define NTHR 512
#define PT 9             // p's per thread per b: p = r*128 + pq
#define NW 8             // waves per block

// R7 champion structure (quad layout: thread (pq,jq) owns
// u_hat[b][p=r*128+pq][jq+4*jj], 72 uh regs; vacc trick: b_logits never
// materialized, bl_it[p] = (sum_{tau<it} v_tau).uh[p] recomputed in the
// softmax pass; quad xor1/2 j-dots; xor4..32 butterfly + dbuf 8-wave LDS
// round for p-sums; sched_barrier(0) spill-guard in build; cap (512,4)).
// R10 deltas:
//  - bid remap: co-resident blocks (consecutive k on an XCD) share s ->
//    both stream the SAME 590 KB W slice in near-lockstep -> trailing
//    block hits L1 -> per-CU L2 traffic ~halves. Per-XCD footprint still
//    4 slices (2.4 MB, L2-fits). Bijective: s = xcd + 8*(k>>6), bp = k&63.
//  - v_rcp_f32 / v_sqrt_f32 intrinsics (R8: bit-neutral).
//  - build addressing by pointer increment (R9: fewer addr VALU).
//  - exp2 with log2e-prescaled vacc (v_exp_f32 is 2^x; saves mul per exp).
__global__ __launch_bounds__(NTHR, 4)
void caps_routing12(const float* __restrict__ x, const float* __restrict__ W,
                    float* __restrict__ out) {
    __shared__ float red[2][NW][2][17];   // [buf][wave][b][j=0..15, 16=esum]

    const int t    = threadIdx.x;
    const int lane = t & 63;
    const int jq   = t & 3;
    const int pq   = t >> 2;
    const int w    = t >> 6;
    const int bid  = blockIdx.x;
    const int xcd  = bid & 7;
    const int k    = bid >> 3;
    const int s    = xcd + ((k >> 6) << 3);   // 4 s-slices per XCD, same-s consecutive
    const int b0   = (k & 63) << 1;

    float uh0[PT][4], uh1[PT][4];

    // ---- build u_hat: per quad, 4 jq lanes cover one p's 512 B of W ----
    {
        const float* wp = W + ((size_t)s * P_SZ + pq) * (DS * DP) + jq * DP;
        const float* xa = x + (size_t)b0 * (P_SZ * DP) + pq * DP;
        const float* xc = xa + P_SZ * DP;
        #pragma unroll
        for (int r = 0; r < PT; ++r) {
            const float4 xa0 = *(const float4*)(xa);
            const float4 xa1 = *(const float4*)(xa + 4);
            const float4 xc0 = *(const float4*)(xc);
            const float4 xc1 = *(const float4*)(xc + 4);
            #pragma unroll
            for (int jj = 0; jj < 4; ++jj) {   // j = jq + 4*jj
                const float4 w0 = *(const float4*)(wp + jj * 32);
                const float4 w1 = *(const float4*)(wp + jj * 32 + 4);
                uh0[r][jj] = w0.x*xa0.x + w0.y*xa0.y + w0.z*xa0.z + w0.w*xa0.w
                           + w1.x*xa1.x + w1.y*xa1.y + w1.z*xa1.z + w1.w*xa1.w;
                uh1[r][jj] = w0.x*xc0.x + w0.y*xc0.y + w0.z*xc0.z + w0.w*xc0.w
                           + w1.x*xc1.x + w1.y*xc1.y + w1.z*xc1.z + w1.w*xc1.w;
            }
            wp += 128 * (DS * DP);
            xa += 128 * DP;
            xc += 128 * DP;
            __builtin_amdgcn_sched_barrier(0);   // cap in-flight loads at 1 iter
        }
    }

    // ---------------- iteration 0: c = 1/P ----------------
    float sv0[4], sv1[4];
    #pragma unroll
    for (int jj = 0; jj < 4; ++jj) {
        float a = 0.f, c = 0.f;
        #pragma unroll
        for (int r = 0; r < PT; ++r) { a += uh0[r][jj]; c += uh1[r][jj]; }
        sv0[jj] = a; sv1[jj] = c;
    }
    #pragma unroll
    for (int off = 4; off < 64; off <<= 1) {
        #pragma unroll
        for (int jj = 0; jj < 4; ++jj) {
            sv0[jj] += __shfl_xor(sv0[jj], off);
            sv1[jj] += __shfl_xor(sv1[jj], off);
        }
    }
    if (lane < 4) {
        #pragma unroll
        for (int jj = 0; jj < 4; ++jj) {
            red[0][w][0][jq + 4*jj] = sv0[jj];
            red[0][w][1][jq + 4*jj] = sv1[jj];
        }
    }
    __syncthreads();
    #pragma unroll
    for (int jj = 0; jj < 4; ++jj) { sv0[jj] = 0.f; sv1[jj] = 0.f; }
    #pragma unroll
    for (int ww = 0; ww < NW; ++ww) {
        #pragma unroll
        for (int jj = 0; jj < 4; ++jj) {
            sv0[jj] += red[0][ww][0][jq + 4*jj];   // same-address broadcast reads
            sv1[jj] += red[0][ww][1][jq + 4*jj];
        }
    }
    #pragma unroll
    for (int jj = 0; jj < 4; ++jj) { sv0[jj] *= (1.f / P_SZ); sv1[jj] *= (1.f / P_SZ); }

    float sq0 = sv0[0]*sv0[0] + sv0[1]*sv0[1] + sv0[2]*sv0[2] + sv0[3]*sv0[3];
    float sq1 = sv1[0]*sv1[0] + sv1[1]*sv1[1] + sv1[2]*sv1[2] + sv1[3]*sv1[3];
    sq0 += __shfl_xor(sq0, 1); sq0 += __shfl_xor(sq0, 2);
    sq1 += __shfl_xor(sq1, 1); sq1 += __shfl_xor(sq1, 2);
    float f0 = sq0 * __builtin_amdgcn_rcpf(
        (1.f + sq0) * (__builtin_amdgcn_sqrtf(sq0) + 1e-7f));
    float f1 = sq1 * __builtin_amdgcn_rcpf(
        (1.f + sq1) * (__builtin_amdgcn_sqrtf(sq1) + 1e-7f));
    // vacc = accumulated v across iterations (replaces b_logits entirely)
    float va0[4], va1[4];
    #pragma unroll
    for (int jj = 0; jj < 4; ++jj) { va0[jj] = f0 * sv0[jj]; va1[jj] = f1 * sv1[jj]; }

    const float LOG2E = 1.4426950408889634f;

    // ---------------- iterations 1, 2 ----------------
    #pragma unroll
    for (int it = 1; it < 3; ++it) {
        float es0 = 0.f, es1 = 0.f;
        float vas0[4], vas1[4];
        #pragma unroll
        for (int jj = 0; jj < 4; ++jj) {
            vas0[jj] = va0[jj] * LOG2E; vas1[jj] = va1[jj] * LOG2E;
            sv0[jj] = 0.f; sv1[jj] = 0.f;
        }
        // fused: logit (= vacc . uh, quad-reduced) -> exp2 -> softmax num+denom
        #pragma unroll
        for (int r = 0; r < PT; ++r) {
            float d0 = vas0[0]*uh0[r][0] + vas0[1]*uh0[r][1]
                     + vas0[2]*uh0[r][2] + vas0[3]*uh0[r][3];
            float d1 = vas1[0]*uh1[r][0] + vas1[1]*uh1[r][1]
                     + vas1[2]*uh1[r][2] + vas1[3]*uh1[r][3];
            d0 += __shfl_xor(d0, 1); d0 += __shfl_xor(d0, 2);
            d1 += __shfl_xor(d1, 1); d1 += __shfl_xor(d1, 2);
            const float e0 = __builtin_amdgcn_exp2f(d0);
            const float e1 = __builtin_amdgcn_exp2f(d1);
            es0 += e0; es1 += e1;
            #pragma unroll
            for (int jj = 0; jj < 4; ++jj) {
                sv0[jj] += e0 * uh0[r][jj];
                sv1[jj] += e1 * uh1[r][jj];
            }
        }
        #pragma unroll
        for (int off = 4; off < 64; off <<= 1) {   // joint 10-value wave reduce
            es0 += __shfl_xor(es0, off);
            es1 += __shfl_xor(es1, off);
            #pragma unroll
            for (int jj = 0; jj < 4; ++jj) {
                sv0[jj] += __shfl_xor(sv0[jj], off);
                sv1[jj] += __shfl_xor(sv1[jj], off);
            }
        }
        const int buf = it & 1;
        if (lane < 4) {
            #pragma unroll
            for (int jj = 0; jj < 4; ++jj) {
                red[buf][w][0][jq + 4*jj] = sv0[jj];
                red[buf][w][1][jq + 4*jj] = sv1[jj];
            }
            if (lane == 0) { red[buf][w][0][16] = es0; red[buf][w][1][16] = es1; }
        }
        __syncthreads();
        es0 = 0.f; es1 = 0.f;
        #pragma unroll
        for (int jj = 0; jj < 4; ++jj) { sv0[jj] = 0.f; sv1[jj] = 0.f; }
        #pragma unroll
        for (int ww = 0; ww < NW; ++ww) {
            es0 += red[buf][ww][0][16];
            es1 += red[buf][ww][1][16];
            #pragma unroll
            for (int jj = 0; jj < 4; ++jj) {
                sv0[jj] += red[buf][ww][0][jq + 4*jj];
                sv1[jj] += red[buf][ww][1][jq + 4*jj];
            }
        }
        const float r0 = __builtin_amdgcn_rcpf(es0);
        const float r1 = __builtin_amdgcn_rcpf(es1);
        #pragma unroll
        for (int jj = 0; jj < 4; ++jj) { sv0[jj] *= r0; sv1[jj] *= r1; }

        sq0 = sv0[0]*sv0[0] + sv0[1]*sv0[1] + sv0[2]*sv0[2] + sv0[3]*sv0[3];
        sq1 = sv1[0]*sv1[0] + sv1[1]*sv1[1] + sv1[2]*sv1[2] + sv1[3]*sv1[3];
        sq0 += __shfl_xor(sq0, 1); sq0 += __shfl_xor(sq0, 2);
        sq1 += __shfl_xor(sq1, 1); sq1 += __shfl_xor(sq1, 2);
        f0 = sq0 * __builtin_amdgcn_rcpf(
            (1.f + sq0) * (__builtin_amdgcn_sqrtf(sq0) + 1e-7f));
        f1 = sq1 * __builtin_amdgcn_rcpf(
            (1.f + sq1) * (__builtin_amdgcn_sqrtf(sq1) + 1e-7f));

        if (it == 2) {
            if (t < 4) {
                #pragma unroll
                for (int jj = 0; jj < 4; ++jj)
                    out[(size_t)(b0 * 32 + s) * DS + jq + 4*jj] = f0 * sv0[jj];
            } else if (t < 8) {
                #pragma unroll
                for (int jj = 0; jj < 4; ++jj)
                    out[(size_t)((b0 + 1) * 32 + s) * DS + jq + 4*jj] = f1 * sv1[jj];
            }
        } else {
            #pragma unroll
            for (int jj = 0; jj < 4; ++jj) {
                va0[jj] += f0 * sv0[jj];
                va1[jj] += f1 * sv1[jj];
            }
        }
    }
}

extern "C" void kernel_launch(void* const* d_in, const int* in_sizes, int n_in,
                              void* d_out, int out_size, void* d_ws, size_t ws_size,
                              hipStream_t stream) {
    const float* x = (const float*)d_in[0];   // (128, 1152, 8) fp32
    const float* W = (const float*)d_in[1];   // (32, 1152, 16, 8) fp32
    float* out = (float*)d_out;               // (128, 32, 16) fp32
    caps_routing12<<<dim3(32 * 64), dim3(NTHR), 0, stream>>>(x, W, out);
}

// Round 11
// 72.315 us; speedup vs baseline: 1.2794x; 1.2794x over previous
//
#include <hip/hip_runtime.h>

#define P_SZ 1152
#define DP 8
#define DS 16
#define NTHR 512
#define PT 9             // p's per thread per b: p = r*128 + pq
#define NW 8             // waves per block

// R7 champion structure + proven-neutral micro-cuts only.
//   Layout: thread (pq=t>>2, jq=t&3) owns u_hat[b][p=r*128+pq][j=jq+4*jj],
//   72 uh regs (2 b's). NB=2 is register-capacity-maximal: per-block uh =
//   147 KB of regfile; 2 blocks/CU = the whole unified VGPR/AGPR file.
//   vacc trick: b_logits never materialized; bl_it[p]=(sum v_tau).uh[p]
//   recomputed in the softmax pass (merged agreement).
//   Mapping s=bid&31: co-resident set per XCD = 4 W slices (2.4 MB) +
//   16 b-pairs x (2.3 MB) ~ L2 size; FETCH 27.7 MB ~ compulsory. (R10's
//   same-s remap pushed x working set to 4.7 MB -> 83 MB FETCH, 3x.)
// R11 deltas (each bit-neutral / free):
//   - v_rcp_f32 / v_sqrt_f32 for all divides (R8: absmax identical).
//   - exp2 with log2e-prescaled vacc (R10: absmax identical).
//   - iter-0 r-sums folded into the build loop (ILP under load latency).
//   - sched_barrier(0) per build r: caps in-flight loads at 1 iter,
//     keeps peak regs < 128 cap -> zero scratch (R7 proof: WRITE=256KB).
__global__ __launch_bounds__(NTHR, 4)
void caps_routing13(const float* __restrict__ x, const float* __restrict__ W,
                    float* __restrict__ out) {
    __shared__ float red[2][NW][2][17];   // [buf][wave][b][j=0..15, 16=esum]

    const int t    = threadIdx.x;
    const int lane = t & 63;
    const int jq   = t & 3;
    const int pq   = t >> 2;
    const int w    = t >> 6;
    const int bid  = blockIdx.x;
    const int s    = bid & 31;            // 4 W-slices per XCD L2
    const int b0   = (bid >> 5) << 1;

    float uh0[PT][4], uh1[PT][4];
    float sv0[4], sv1[4];
    #pragma unroll
    for (int jj = 0; jj < 4; ++jj) { sv0[jj] = 0.f; sv1[jj] = 0.f; }

    const float* xb0 = x + (size_t)b0 * (P_SZ * DP);
    const float* xb1 = xb0 + P_SZ * DP;

    // ---- build u_hat (iter-0 partial sums folded in) ----
    #pragma unroll
    for (int r = 0; r < PT; ++r) {
        const int p = (r << 7) + pq;
        const float* wp = W + (size_t)(s * P_SZ + p) * (DS * DP) + jq * DP;
        const float4 xa0 = *(const float4*)(xb0 + p * DP);
        const float4 xa1 = *(const float4*)(xb0 + p * DP + 4);
        const float4 xc0 = *(const float4*)(xb1 + p * DP);
        const float4 xc1 = *(const float4*)(xb1 + p * DP + 4);
        #pragma unroll
        for (int jj = 0; jj < 4; ++jj) {   // j = jq + 4*jj
            const float4 w0 = *(const float4*)(wp + jj * 32);
            const float4 w1 = *(const float4*)(wp + jj * 32 + 4);
            uh0[r][jj] = w0.x*xa0.x + w0.y*xa0.y + w0.z*xa0.z + w0.w*xa0.w
                       + w1.x*xa1.x + w1.y*xa1.y + w1.z*xa1.z + w1.w*xa1.w;
            uh1[r][jj] = w0.x*xc0.x + w0.y*xc0.y + w0.z*xc0.z + w0.w*xc0.w
                       + w1.x*xc1.x + w1.y*xc1.y + w1.z*xc1.z + w1.w*xc1.w;
            sv0[jj] += uh0[r][jj];
            sv1[jj] += uh1[r][jj];
        }
        __builtin_amdgcn_sched_barrier(0);   // cap in-flight loads at 1 iter
    }

    // ---------------- iteration 0: c = 1/P ----------------
    #pragma unroll
    for (int off = 4; off < 64; off <<= 1) {
        #pragma unroll
        for (int jj = 0; jj < 4; ++jj) {
            sv0[jj] += __shfl_xor(sv0[jj], off);
            sv1[jj] += __shfl_xor(sv1[jj], off);
        }
    }
    if (lane < 4) {
        #pragma unroll
        for (int jj = 0; jj < 4; ++jj) {
            red[0][w][0][jq + 4*jj] = sv0[jj];
            red[0][w][1][jq + 4*jj] = sv1[jj];
        }
    }
    __syncthreads();
    #pragma unroll
    for (int jj = 0; jj < 4; ++jj) { sv0[jj] = 0.f; sv1[jj] = 0.f; }
    #pragma unroll
    for (int ww = 0; ww < NW; ++ww) {
        #pragma unroll
        for (int jj = 0; jj < 4; ++jj) {
            sv0[jj] += red[0][ww][0][jq + 4*jj];   // same-address broadcast reads
            sv1[jj] += red[0][ww][1][jq + 4*jj];
        }
    }
    #pragma unroll
    for (int jj = 0; jj < 4; ++jj) { sv0[jj] *= (1.f / P_SZ); sv1[jj] *= (1.f / P_SZ); }

    float sq0 = sv0[0]*sv0[0] + sv0[1]*sv0[1] + sv0[2]*sv0[2] + sv0[3]*sv0[3];
    float sq1 = sv1[0]*sv1[0] + sv1[1]*sv1[1] + sv1[2]*sv1[2] + sv1[3]*sv1[3];
    sq0 += __shfl_xor(sq0, 1); sq0 += __shfl_xor(sq0, 2);
    sq1 += __shfl_xor(sq1, 1); sq1 += __shfl_xor(sq1, 2);
    float f0 = sq0 * __builtin_amdgcn_rcpf(
        (1.f + sq0) * (__builtin_amdgcn_sqrtf(sq0) + 1e-7f));
    float f1 = sq1 * __builtin_amdgcn_rcpf(
        (1.f + sq1) * (__builtin_amdgcn_sqrtf(sq1) + 1e-7f));
    // vacc = accumulated v across iterations (replaces b_logits entirely)
    float va0[4], va1[4];
    #pragma unroll
    for (int jj = 0; jj < 4; ++jj) { va0[jj] = f0 * sv0[jj]; va1[jj] = f1 * sv1[jj]; }

    const float LOG2E = 1.4426950408889634f;

    // ---------------- iterations 1, 2 ----------------
    #pragma unroll
    for (int it = 1; it < 3; ++it) {
        float es0 = 0.f, es1 = 0.f;
        float vas0[4], vas1[4];
        #pragma unroll
        for (int jj = 0; jj < 4; ++jj) {
            vas0[jj] = va0[jj] * LOG2E; vas1[jj] = va1[jj] * LOG2E;
            sv0[jj] = 0.f; sv1[jj] = 0.f;
        }
        // fused: logit (= vacc . uh, quad-reduced) -> exp2 -> softmax num+denom
        #pragma unroll
        for (int r = 0; r < PT; ++r) {
            float d0 = vas0[0]*uh0[r][0] + vas0[1]*uh0[r][1]
                     + vas0[2]*uh0[r][2] + vas0[3]*uh0[r][3];
            float d1 = vas1[0]*uh1[r][0] + vas1[1]*uh1[r][1]
                     + vas1[2]*uh1[r][2] + vas1[3]*uh1[r][3];
            d0 += __shfl_xor(d0, 1); d0 += __shfl_xor(d0, 2);
            d1 += __shfl_xor(d1, 1); d1 += __shfl_xor(d1, 2);
            const float e0 = __builtin_amdgcn_exp2f(d0);
            const float e1 = __builtin_amdgcn_exp2f(d1);
            es0 += e0; es1 += e1;
            #pragma unroll
            for (int jj = 0; jj < 4; ++jj) {
                sv0[jj] += e0 * uh0[r][jj];
                sv1[jj] += e1 * uh1[r][jj];
            }
        }
        #pragma unroll
        for (int off = 4; off < 64; off <<= 1) {   // joint 10-value wave reduce
            es0 += __shfl_xor(es0, off);
            es1 += __shfl_xor(es1, off);
            #pragma unroll
            for (int jj = 0; jj < 4; ++jj) {
                sv0[jj] += __shfl_xor(sv0[jj], off);
                sv1[jj] += __shfl_xor(sv1[jj], off);
            }
        }
        const int buf = it & 1;
        if (lane < 4) {
            #pragma unroll
            for (int jj = 0; jj < 4; ++jj) {
                red[buf][w][0][jq + 4*jj] = sv0[jj];
                red[buf][w][1][jq + 4*jj] = sv1[jj];
            }
            if (lane == 0) { red[buf][w][0][16] = es0; red[buf][w][1][16] = es1; }
        }
        __syncthreads();
        es0 = 0.f; es1 = 0.f;
        #pragma unroll
        for (int jj = 0; jj < 4; ++jj) { sv0[jj] = 0.f; sv1[jj] = 0.f; }
        #pragma unroll
        for (int ww = 0; ww < NW; ++ww) {
            es0 += red[buf][ww][0][16];
            es1 += red[buf][ww][1][16];
            #pragma unroll
            for (int jj = 0; jj < 4; ++jj) {
                sv0[jj] += red[buf][ww][0][jq + 4*jj];
                sv1[jj] += red[buf][ww][1][jq + 4*jj];
            }
        }
        const float r0 = __builtin_amdgcn_rcpf(es0);
        const float r1 = __builtin_amdgcn_rcpf(es1);
        #pragma unroll
        for (int jj = 0; jj < 4; ++jj) { sv0[jj] *= r0; sv1[jj] *= r1; }

        sq0 = sv0[0]*sv0[0] + sv0[1]*sv0[1] + sv0[2]*sv0[2] + sv0[3]*sv0[3];
        sq1 = sv1[0]*sv1[0] + sv1[1]*sv1[1] + sv1[2]*sv1[2] + sv1[3]*sv1[3];
        sq0 += __shfl_xor(sq0, 1); sq0 += __shfl_xor(sq0, 2);
        sq1 += __shfl_xor(sq1, 1); sq1 += __shfl_xor(sq1, 2);
        f0 = sq0 * __builtin_amdgcn_rcpf(
            (1.f + sq0) * (__builtin_amdgcn_sqrtf(sq0) + 1e-7f));
        f1 = sq1 * __builtin_amdgcn_rcpf(
            (1.f + sq1) * (__builtin_amdgcn_sqrtf(sq1) + 1e-7f));

        if (it == 2) {
            if (t < 4) {
                #pragma unroll
                for (int jj = 0; jj < 4; ++jj)
                    out[(size_t)(b0 * 32 + s) * DS + jq + 4*jj] = f0 * sv0[jj];
            } else if (t < 8) {
                #pragma unroll
                for (int jj = 0; jj < 4; ++jj)
                    out[(size_t)((b0 + 1) * 32 + s) * DS + jq + 4*jj] = f1 * sv1[jj];
            }
        } else {
            #pragma unroll
            for (int jj = 0; jj < 4; ++jj) {
                va0[jj] += f0 * sv0[jj];
                va1[jj] += f1 * sv1[jj];
            }
        }
    }
}

extern "C" void kernel_launch(void* const* d_in, const int* in_sizes, int n_in,
                              void* d_out, int out_size, void* d_ws, size_t ws_size,
                              hipStream_t stream) {
    const float* x = (const float*)d_in[0];   // (128, 1152, 8) fp32
    const float* W = (const float*)d_in[1];   // (32, 1152, 16, 8) fp32
    float* out = (float*)d_out;               // (128, 32, 16) fp32
    caps_routing13<<<dim3(32 * 64), dim3(NTHR), 0, stream>>>(x, W, out);
}

// Round 12
// 69.073 us; speedup vs baseline: 1.3394x; 1.0469x over previous
//
#include <hip/hip_runtime.h>

#define P_SZ 1152
#define DP 8
#define DS 16
#define NTHR 512
#define PT 9             // p's per thread per b: p = r*128 + pq
#define NW 8             // waves per block

// R11 champion (72.3 us) + DPP quad reduces.
//   Structure frozen: quad layout (thread (pq,jq) owns
//   u_hat[b][p=r*128+pq][j=jq+4*jj], 72 uh regs, 2 b's); vacc trick
//   (b_logits = (sum v_tau).uh recomputed in softmax pass); s=bid&31
//   mapping (4 W-slices + 16 b-pairs co-resident per XCD L2 - proven
//   optimal in R10 both directions); sched_barrier(0) spill guard;
//   rcp/sqrt/exp2 fast intrinsics (bit-neutral, R8/R10); iter-0 sums
//   folded into build (R11); cap (512,4), 2 blocks/CU.
// R12 delta: the quad xor1/xor2 reduces (d0/d1 before each exp2, sq0/sq1
//   before each squash) were ds_swizzle (LDS pipe, ~30cy, on the exp
//   dependency chain). DPP quad_perm does the same exchange on the VALU
//   pipe in ~1cy: xor1 = quad_perm[1,0,3,2] (0xB1), xor2 = quad_perm
//   [2,3,0,1] (0x4E). Bit-identical add order. Wave butterfly (xor4..32)
//   stays ds_swizzle (no 64-lane DPP pattern).
__device__ __forceinline__ float qxor1_add(float v) {
    const int t = __builtin_amdgcn_update_dpp(0, __float_as_int(v),
                                              0xB1, 0xF, 0xF, true);
    return v + __int_as_float(t);
}
__device__ __forceinline__ float qxor2_add(float v) {
    const int t = __builtin_amdgcn_update_dpp(0, __float_as_int(v),
                                              0x4E, 0xF, 0xF, true);
    return v + __int_as_float(t);
}

__global__ __launch_bounds__(NTHR, 4)
void caps_routing14(const float* __restrict__ x, const float* __restrict__ W,
                    float* __restrict__ out) {
    __shared__ float red[2][NW][2][17];   // [buf][wave][b][j=0..15, 16=esum]

    const int t    = threadIdx.x;
    const int lane = t & 63;
    const int jq   = t & 3;
    const int pq   = t >> 2;
    const int w    = t >> 6;
    const int bid  = blockIdx.x;
    const int s    = bid & 31;            // 4 W-slices per XCD L2
    const int b0   = (bid >> 5) << 1;

    float uh0[PT][4], uh1[PT][4];
    float sv0[4], sv1[4];
    #pragma unroll
    for (int jj = 0; jj < 4; ++jj) { sv0[jj] = 0.f; sv1[jj] = 0.f; }

    const float* xb0 = x + (size_t)b0 * (P_SZ * DP);
    const float* xb1 = xb0 + P_SZ * DP;

    // ---- build u_hat (iter-0 partial sums folded in) ----
    #pragma unroll
    for (int r = 0; r < PT; ++r) {
        const int p = (r << 7) + pq;
        const float* wp = W + (size_t)(s * P_SZ + p) * (DS * DP) + jq * DP;
        const float4 xa0 = *(const float4*)(xb0 + p * DP);
        const float4 xa1 = *(const float4*)(xb0 + p * DP + 4);
        const float4 xc0 = *(const float4*)(xb1 + p * DP);
        const float4 xc1 = *(const float4*)(xb1 + p * DP + 4);
        #pragma unroll
        for (int jj = 0; jj < 4; ++jj) {   // j = jq + 4*jj
            const float4 w0 = *(const float4*)(wp + jj * 32);
            const float4 w1 = *(const float4*)(wp + jj * 32 + 4);
            uh0[r][jj] = w0.x*xa0.x + w0.y*xa0.y + w0.z*xa0.z + w0.w*xa0.w
                       + w1.x*xa1.x + w1.y*xa1.y + w1.z*xa1.z + w1.w*xa1.w;
            uh1[r][jj] = w0.x*xc0.x + w0.y*xc0.y + w0.z*xc0.z + w0.w*xc0.w
                       + w1.x*xc1.x + w1.y*xc1.y + w1.z*xc1.z + w1.w*xc1.w;
            sv0[jj] += uh0[r][jj];
            sv1[jj] += uh1[r][jj];
        }
        __builtin_amdgcn_sched_barrier(0);   // cap in-flight loads at 1 iter
    }

    // ---------------- iteration 0: c = 1/P ----------------
    #pragma unroll
    for (int off = 4; off < 64; off <<= 1) {
        #pragma unroll
        for (int jj = 0; jj < 4; ++jj) {
            sv0[jj] += __shfl_xor(sv0[jj], off);
            sv1[jj] += __shfl_xor(sv1[jj], off);
        }
    }
    if (lane < 4) {
        #pragma unroll
        for (int jj = 0; jj < 4; ++jj) {
            red[0][w][0][jq + 4*jj] = sv0[jj];
            red[0][w][1][jq + 4*jj] = sv1[jj];
        }
    }
    __syncthreads();
    #pragma unroll
    for (int jj = 0; jj < 4; ++jj) { sv0[jj] = 0.f; sv1[jj] = 0.f; }
    #pragma unroll
    for (int ww = 0; ww < NW; ++ww) {
        #pragma unroll
        for (int jj = 0; jj < 4; ++jj) {
            sv0[jj] += red[0][ww][0][jq + 4*jj];   // same-address broadcast reads
            sv1[jj] += red[0][ww][1][jq + 4*jj];
        }
    }
    #pragma unroll
    for (int jj = 0; jj < 4; ++jj) { sv0[jj] *= (1.f / P_SZ); sv1[jj] *= (1.f / P_SZ); }

    float sq0 = sv0[0]*sv0[0] + sv0[1]*sv0[1] + sv0[2]*sv0[2] + sv0[3]*sv0[3];
    float sq1 = sv1[0]*sv1[0] + sv1[1]*sv1[1] + sv1[2]*sv1[2] + sv1[3]*sv1[3];
    sq0 = qxor2_add(qxor1_add(sq0));
    sq1 = qxor2_add(qxor1_add(sq1));
    float f0 = sq0 * __builtin_amdgcn_rcpf(
        (1.f + sq0) * (__builtin_amdgcn_sqrtf(sq0) + 1e-7f));
    float f1 = sq1 * __builtin_amdgcn_rcpf(
        (1.f + sq1) * (__builtin_amdgcn_sqrtf(sq1) + 1e-7f));
    // vacc = accumulated v across iterations (replaces b_logits entirely)
    float va0[4], va1[4];
    #pragma unroll
    for (int jj = 0; jj < 4; ++jj) { va0[jj] = f0 * sv0[jj]; va1[jj] = f1 * sv1[jj]; }

    const float LOG2E = 1.4426950408889634f;

    // ---------------- iterations 1, 2 ----------------
    #pragma unroll
    for (int it = 1; it < 3; ++it) {
        float es0 = 0.f, es1 = 0.f;
        float vas0[4], vas1[4];
        #pragma unroll
        for (int jj = 0; jj < 4; ++jj) {
            vas0[jj] = va0[jj] * LOG2E; vas1[jj] = va1[jj] * LOG2E;
            sv0[jj] = 0.f; sv1[jj] = 0.f;
        }
        // fused: logit (= vacc . uh, DPP quad-reduced) -> exp2 -> num+denom
        #pragma unroll
        for (int r = 0; r < PT; ++r) {
            float d0 = vas0[0]*uh0[r][0] + vas0[1]*uh0[r][1]
                     + vas0[2]*uh0[r][2] + vas0[3]*uh0[r][3];
            float d1 = vas1[0]*uh1[r][0] + vas1[1]*uh1[r][1]
                     + vas1[2]*uh1[r][2] + vas1[3]*uh1[r][3];
            d0 = qxor2_add(qxor1_add(d0));
            d1 = qxor2_add(qxor1_add(d1));
            const float e0 = __builtin_amdgcn_exp2f(d0);
            const float e1 = __builtin_amdgcn_exp2f(d1);
            es0 += e0; es1 += e1;
            #pragma unroll
            for (int jj = 0; jj < 4; ++jj) {
                sv0[jj] += e0 * uh0[r][jj];
                sv1[jj] += e1 * uh1[r][jj];
            }
        }
        #pragma unroll
        for (int off = 4; off < 64; off <<= 1) {   // joint 10-value wave reduce
            es0 += __shfl_xor(es0, off);
            es1 += __shfl_xor(es1, off);
            #pragma unroll
            for (int jj = 0; jj < 4; ++jj) {
                sv0[jj] += __shfl_xor(sv0[jj], off);
                sv1[jj] += __shfl_xor(sv1[jj], off);
            }
        }
        const int buf = it & 1;
        if (lane < 4) {
            #pragma unroll
            for (int jj = 0; jj < 4; ++jj) {
                red[buf][w][0][jq + 4*jj] = sv0[jj];
                red[buf][w][1][jq + 4*jj] = sv1[jj];
            }
            if (lane == 0) { red[buf][w][0][16] = es0; red[buf][w][1][16] = es1; }
        }
        __syncthreads();
        es0 = 0.f; es1 = 0.f;
        #pragma unroll
        for (int jj = 0; jj < 4; ++jj) { sv0[jj] = 0.f; sv1[jj] = 0.f; }
        #pragma unroll
        for (int ww = 0; ww < NW; ++ww) {
            es0 += red[buf][ww][0][16];
            es1 += red[buf][ww][1][16];
            #pragma unroll
            for (int jj = 0; jj < 4; ++jj) {
                sv0[jj] += red[buf][ww][0][jq + 4*jj];
                sv1[jj] += red[buf][ww][1][jq + 4*jj];
            }
        }
        const float r0 = __builtin_amdgcn_rcpf(es0);
        const float r1 = __builtin_amdgcn_rcpf(es1);
        #pragma unroll
        for (int jj = 0; jj < 4; ++jj) { sv0[jj] *= r0; sv1[jj] *= r1; }

        sq0 = sv0[0]*sv0[0] + sv0[1]*sv0[1] + sv0[2]*sv0[2] + sv0[3]*sv0[3];
        sq1 = sv1[0]*sv1[0] + sv1[1]*sv1[1] + sv1[2]*sv1[2] + sv1[3]*sv1[3];
        sq0 = qxor2_add(qxor1_add(sq0));
        sq1 = qxor2_add(qxor1_add(sq1));
        f0 = sq0 * __builtin_amdgcn_rcpf(
            (1.f + sq0) * (__builtin_amdgcn_sqrtf(sq0) + 1e-7f));
        f1 = sq1 * __builtin_amdgcn_rcpf(
            (1.f + sq1) * (__builtin_amdgcn_sqrtf(sq1) + 1e-7f));

        if (it == 2) {
            if (t < 4) {
                #pragma unroll
                for (int jj = 0; jj < 4; ++jj)
                    out[(size_t)(b0 * 32 + s) * DS + jq + 4*jj] = f0 * sv0[jj];
            } else if (t < 8) {
                #pragma unroll
                for (int jj = 0; jj < 4; ++jj)
                    out[(size_t)((b0 + 1) * 32 + s) * DS + jq + 4*jj] = f1 * sv1[jj];
            }
        } else {
            #pragma unroll
            for (int jj = 0; jj < 4; ++jj) {
                va0[jj] += f0 * sv0[jj];
                va1[jj] += f1 * sv1[jj];
            }
        }
    }
}

extern "C" void kernel_launch(void* const* d_in, const int* in_sizes, int n_in,
                              void* d_out, int out_size, void* d_ws, size_t ws_size,
                              hipStream_t stream) {
    const float* x = (const float*)d_in[0];   // (128, 1152, 8) fp32
    const float* W = (const float*)d_in[1];   // (32, 1152, 16, 8) fp32
    float* out = (float*)d_out;               // (128, 32, 16) fp32
    caps_routing14<<<dim3(32 * 64), dim3(NTHR), 0, stream>>>(x, W, out);
}

// Round 13
// 67.488 us; speedup vs baseline: 1.3709x; 1.0235x over previous
//
#include <hip/hip_runtime.h>

#define P_SZ 1152
#define DP 8
#define DS 16
#define NTHR 512
#define PT 9             // p's per thread per b: p = r*128 + pq
#define NW 8             // waves per block

// R12 champion (69.1 us) + de-LDS'd wave butterfly.
//   Structure frozen: quad layout (thread (pq,jq) owns
//   u_hat[b][p=r*128+pq][j=jq+4*jj], 72 uh regs, 2 b's); vacc trick
//   (b_logits = (sum v_tau).uh recomputed in softmax pass); s=bid&31
//   mapping (proven optimal R10); sched_barrier(0) spill guard;
//   rcp/sqrt/exp2 fast intrinsics; iter-0 sums folded into build;
//   DPP quad_perm xor1/xor2 (R12); cap (512,4), 2 blocks/CU.
// R13 delta: wave butterfly levels 4/8/32 leave the LDS pipe too.
//   xor4 -> DPP row_ror:4 (0x124), xor8 -> DPP row_ror:8 (0x128):
//   rotations by multiples of 4 keep jq-alignment; per-lane add order
//   permutes across quads but consumed lanes (0-3) hold the full sum.
//   xor32 -> v_permlane32_swap(x,x): returns {lo-half dup, hi-half dup};
//   sum = xor32 butterfly on the VALU pipe, uniform add order.
//   xor16 stays ds_swizzle (no row-crossing DPP; permlane16_swap riskier).
//   Chain per value: 4 ds ops -> 1 ds + 3 VALU-pipe ops.
__device__ __forceinline__ float qxor1_add(float v) {
    const int t = __builtin_amdgcn_update_dpp(0, __float_as_int(v),
                                              0xB1, 0xF, 0xF, true);
    return v + __int_as_float(t);
}
__device__ __forceinline__ float qxor2_add(float v) {
    const int t = __builtin_amdgcn_update_dpp(0, __float_as_int(v),
                                              0x4E, 0xF, 0xF, true);
    return v + __int_as_float(t);
}
__device__ __forceinline__ float ror4_add(float v) {
    const int t = __builtin_amdgcn_update_dpp(0, __float_as_int(v),
                                              0x124, 0xF, 0xF, true);
    return v + __int_as_float(t);
}
__device__ __forceinline__ float ror8_add(float v) {
    const int t = __builtin_amdgcn_update_dpp(0, __float_as_int(v),
                                              0x128, 0xF, 0xF, true);
    return v + __int_as_float(t);
}
__device__ __forceinline__ float x32_add(float v) {
    const unsigned u = __float_as_uint(v);
    auto p = __builtin_amdgcn_permlane32_swap(u, u, false, false);
    return __uint_as_float(p[0]) + __uint_as_float(p[1]);
}
// full cross-quad reduce (sums the 16 quads; valid in lanes 0-3 at least)
__device__ __forceinline__ float quadred(float v) {
    v = ror4_add(v);
    v = ror8_add(v);
    v += __shfl_xor(v, 16);
    return x32_add(v);
}

__global__ __launch_bounds__(NTHR, 4)
void caps_routing15(const float* __restrict__ x, const float* __restrict__ W,
                    float* __restrict__ out) {
    __shared__ float red[2][NW][2][17];   // [buf][wave][b][j=0..15, 16=esum]

    const int t    = threadIdx.x;
    const int lane = t & 63;
    const int jq   = t & 3;
    const int pq   = t >> 2;
    const int w    = t >> 6;
    const int bid  = blockIdx.x;
    const int s    = bid & 31;            // 4 W-slices per XCD L2
    const int b0   = (bid >> 5) << 1;

    float uh0[PT][4], uh1[PT][4];
    float sv0[4], sv1[4];
    #pragma unroll
    for (int jj = 0; jj < 4; ++jj) { sv0[jj] = 0.f; sv1[jj] = 0.f; }

    const float* xb0 = x + (size_t)b0 * (P_SZ * DP);
    const float* xb1 = xb0 + P_SZ * DP;

    // ---- build u_hat (iter-0 partial sums folded in) ----
    #pragma unroll
    for (int r = 0; r < PT; ++r) {
        const int p = (r << 7) + pq;
        const float* wp = W + (size_t)(s * P_SZ + p) * (DS * DP) + jq * DP;
        const float4 xa0 = *(const float4*)(xb0 + p * DP);
        const float4 xa1 = *(const float4*)(xb0 + p * DP + 4);
        const float4 xc0 = *(const float4*)(xb1 + p * DP);
        const float4 xc1 = *(const float4*)(xb1 + p * DP + 4);
        #pragma unroll
        for (int jj = 0; jj < 4; ++jj) {   // j = jq + 4*jj
            const float4 w0 = *(const float4*)(wp + jj * 32);
            const float4 w1 = *(const float4*)(wp + jj * 32 + 4);
            uh0[r][jj] = w0.x*xa0.x + w0.y*xa0.y + w0.z*xa0.z + w0.w*xa0.w
                       + w1.x*xa1.x + w1.y*xa1.y + w1.z*xa1.z + w1.w*xa1.w;
            uh1[r][jj] = w0.x*xc0.x + w0.y*xc0.y + w0.z*xc0.z + w0.w*xc0.w
                       + w1.x*xc1.x + w1.y*xc1.y + w1.z*xc1.z + w1.w*xc1.w;
            sv0[jj] += uh0[r][jj];
            sv1[jj] += uh1[r][jj];
        }
        __builtin_amdgcn_sched_barrier(0);   // cap in-flight loads at 1 iter
    }

    // ---------------- iteration 0: c = 1/P ----------------
    #pragma unroll
    for (int jj = 0; jj < 4; ++jj) {
        sv0[jj] = quadred(sv0[jj]);
        sv1[jj] = quadred(sv1[jj]);
    }
    if (lane < 4) {
        #pragma unroll
        for (int jj = 0; jj < 4; ++jj) {
            red[0][w][0][jq + 4*jj] = sv0[jj];
            red[0][w][1][jq + 4*jj] = sv1[jj];
        }
    }
    __syncthreads();
    #pragma unroll
    for (int jj = 0; jj < 4; ++jj) { sv0[jj] = 0.f; sv1[jj] = 0.f; }
    #pragma unroll
    for (int ww = 0; ww < NW; ++ww) {
        #pragma unroll
        for (int jj = 0; jj < 4; ++jj) {
            sv0[jj] += red[0][ww][0][jq + 4*jj];   // same-address broadcast reads
            sv1[jj] += red[0][ww][1][jq + 4*jj];
        }
    }
    #pragma unroll
    for (int jj = 0; jj < 4; ++jj) { sv0[jj] *= (1.f / P_SZ); sv1[jj] *= (1.f / P_SZ); }

    float sq0 = sv0[0]*sv0[0] + sv0[1]*sv0[1] + sv0[2]*sv0[2] + sv0[3]*sv0[3];
    float sq1 = sv1[0]*sv1[0] + sv1[1]*sv1[1] + sv1[2]*sv1[2] + sv1[3]*sv1[3];
    sq0 = qxor2_add(qxor1_add(sq0));
    sq1 = qxor2_add(qxor1_add(sq1));
    float f0 = sq0 * __builtin_amdgcn_rcpf(
        (1.f + sq0) * (__builtin_amdgcn_sqrtf(sq0) + 1e-7f));
    float f1 = sq1 * __builtin_amdgcn_rcpf(
        (1.f + sq1) * (__builtin_amdgcn_sqrtf(sq1) + 1e-7f));
    // vacc = accumulated v across iterations (replaces b_logits entirely)
    float va0[4], va1[4];
    #pragma unroll
    for (int jj = 0; jj < 4; ++jj) { va0[jj] = f0 * sv0[jj]; va1[jj] = f1 * sv1[jj]; }

    const float LOG2E = 1.4426950408889634f;

    // ---------------- iterations 1, 2 ----------------
    #pragma unroll
    for (int it = 1; it < 3; ++it) {
        float es0 = 0.f, es1 = 0.f;
        float vas0[4], vas1[4];
        #pragma unroll
        for (int jj = 0; jj < 4; ++jj) {
            vas0[jj] = va0[jj] * LOG2E; vas1[jj] = va1[jj] * LOG2E;
            sv0[jj] = 0.f; sv1[jj] = 0.f;
        }
        // fused: logit (= vacc . uh, DPP quad-reduced) -> exp2 -> num+denom
        #pragma unroll
        for (int r = 0; r < PT; ++r) {
            float d0 = vas0[0]*uh0[r][0] + vas0[1]*uh0[r][1]
                     + vas0[2]*uh0[r][2] + vas0[3]*uh0[r][3];
            float d1 = vas1[0]*uh1[r][0] + vas1[1]*uh1[r][1]
                     + vas1[2]*uh1[r][2] + vas1[3]*uh1[r][3];
            d0 = qxor2_add(qxor1_add(d0));
            d1 = qxor2_add(qxor1_add(d1));
            const float e0 = __builtin_amdgcn_exp2f(d0);
            const float e1 = __builtin_amdgcn_exp2f(d1);
            es0 += e0; es1 += e1;
            #pragma unroll
            for (int jj = 0; jj < 4; ++jj) {
                sv0[jj] += e0 * uh0[r][jj];
                sv1[jj] += e1 * uh1[r][jj];
            }
        }
        // cross-quad reduce (10 values), mostly VALU-pipe
        es0 = quadred(es0);
        es1 = quadred(es1);
        #pragma unroll
        for (int jj = 0; jj < 4; ++jj) {
            sv0[jj] = quadred(sv0[jj]);
            sv1[jj] = quadred(sv1[jj]);
        }
        const int buf = it & 1;
        if (lane < 4) {
            #pragma unroll
            for (int jj = 0; jj < 4; ++jj) {
                red[buf][w][0][jq + 4*jj] = sv0[jj];
                red[buf][w][1][jq + 4*jj] = sv1[jj];
            }
            if (lane == 0) { red[buf][w][0][16] = es0; red[buf][w][1][16] = es1; }
        }
        __syncthreads();
        es0 = 0.f; es1 = 0.f;
        #pragma unroll
        for (int jj = 0; jj < 4; ++jj) { sv0[jj] = 0.f; sv1[jj] = 0.f; }
        #pragma unroll
        for (int ww = 0; ww < NW; ++ww) {
            es0 += red[buf][ww][0][16];
            es1 += red[buf][ww][1][16];
            #pragma unroll
            for (int jj = 0; jj < 4; ++jj) {
                sv0[jj] += red[buf][ww][0][jq + 4*jj];
                sv1[jj] += red[buf][ww][1][jq + 4*jj];
            }
        }
        const float r0 = __builtin_amdgcn_rcpf(es0);
        const float r1 = __builtin_amdgcn_rcpf(es1);
        #pragma unroll
        for (int jj = 0; jj < 4; ++jj) { sv0[jj] *= r0; sv1[jj] *= r1; }

        sq0 = sv0[0]*sv0[0] + sv0[1]*sv0[1] + sv0[2]*sv0[2] + sv0[3]*sv0[3];
        sq1 = sv1[0]*sv1[0] + sv1[1]*sv1[1] + sv1[2]*sv1[2] + sv1[3]*sv1[3];
        sq0 = qxor2_add(qxor1_add(sq0));
        sq1 = qxor2_add(qxor1_add(sq1));
        f0 = sq0 * __builtin_amdgcn_rcpf(
            (1.f + sq0) * (__builtin_amdgcn_sqrtf(sq0) + 1e-7f));
        f1 = sq1 * __builtin_amdgcn_rcpf(
            (1.f + sq1) * (__builtin_amdgcn_sqrtf(sq1) + 1e-7f));

        if (it == 2) {
            if (t < 4) {
                #pragma unroll
                for (int jj = 0; jj < 4; ++jj)
                    out[(size_t)(b0 * 32 + s) * DS + jq + 4*jj] = f0 * sv0[jj];
            } else if (t < 8) {
                #pragma unroll
                for (int jj = 0; jj < 4; ++jj)
                    out[(size_t)((b0 + 1) * 32 + s) * DS + jq + 4*jj] = f1 * sv1[jj];
            }
        } else {
            #pragma unroll
            for (int jj = 0; jj < 4; ++jj) {
                va0[jj] += f0 * sv0[jj];
                va1[jj] += f1 * sv1[jj];
            }
        }
    }
}

extern "C" void kernel_launch(void* const* d_in, const int* in_sizes, int n_in,
                              void* d_out, int out_size, void* d_ws, size_t ws_size,
                              hipStream_t stream) {
    const float* x = (const float*)d_in[0];   // (128, 1152, 8) fp32
    const float* W = (const float*)d_in[1];   // (32, 1152, 16, 8) fp32
    float* out = (float*)d_out;               // (128, 32, 16) fp32
    caps_routing15<<<dim3(32 * 64), dim3(NTHR), 0, stream>>>(x, W, out);
}